// Round 11
// baseline (34.140 us; speedup 1.0000x reference)
//
#include <hip/hip_runtime.h>
#include <math.h>

#define NENT 33          // tap entries 0..32
#define NQ   30          // quad records e = taps (e..e+3), e = 0..29
#define PPT  8
#define NBLK 2048

__device__ __forceinline__ unsigned short f2bf(float f) {
    unsigned int b = __float_as_uint(f);
    unsigned int r = (b + 0x7FFFu + ((b >> 16) & 1u)) >> 16;   // RNE
    return (unsigned short)r;
}
__device__ __forceinline__ float bflo(unsigned int w) { return __uint_as_float(w << 16); }
__device__ __forceinline__ float bfhi(unsigned int w) { return __uint_as_float(w & 0xFFFF0000u); }

__global__ __launch_bounds__(256) void yuksel_fused(
    const float* __restrict__ x, const float* __restrict__ P,
    float* __restrict__ out, int N)
{
    __shared__ float stage[5][NENT];
    __shared__ uint2 qtab[5][NQ];     // bf16x4: taps e..e+3, one ds_read_b64 each
    const int tid = threadIdx.x;

    // ---- phase A: 33 parallel entry tasks ----
    if (tid < NENT) {
        const int e = tid;
        float vals[5];
        if (e == 1) {
            float r0[5], r1[5], r2[5];
            for (int r = 0; r < 3; ++r) {
                float* dst = r==0 ? r0 : (r==1 ? r1 : r2);
                float a = P[r*5+2], b = P[r*5+3], c = P[r*5+4];
                dst[0] = P[r*5+0]; dst[1] = P[r*5+1];
                dst[2] = a*a + b*b; dst[3] = b*(a+c); dst[4] = b*b + c*c;
            }
            for (int k = 0; k < 2; ++k) vals[k] = (r0[k]+r2[k])*0.25f   + r1[k]*0.5f;
            for (int k = 2; k < 5; ++k) vals[k] = (r0[k]+r2[k])*0.0625f + r1[k]*0.25f;
        } else {
            float a = P[e*5+2], b = P[e*5+3], c = P[e*5+4];
            vals[0] = P[e*5+0]; vals[1] = P[e*5+1];
            vals[2] = a*a + b*b; vals[3] = b*(a+c); vals[4] = b*b + c*c;
        }
#pragma unroll
        for (int k = 0; k < 5; ++k) stage[k][e] = vals[k];
    }
    __syncthreads();

    // ---- phase B: 150 parallel bf16x4 pack tasks ----
    if (tid < 5*NQ) {
        const int k = tid / NQ, e = tid % NQ;
        unsigned int h0 = f2bf(stage[k][e+0]), h1 = f2bf(stage[k][e+1]);
        unsigned int h2 = f2bf(stage[k][e+2]), h3 = f2bf(stage[k][e+3]);
        qtab[k][e] = make_uint2(h0 | (h1 << 16), h2 | (h3 << 16));
    }
    __syncthreads();

    // ---- single-pass eval: 8 points per thread, one iteration ----
    const int gid = blockIdx.x * 256 + tid;
    int j0 = gid * PPT;
    if (j0 >= N) return;

    // both x-loads issue immediately (2x read MLP)
    const float4* xp = reinterpret_cast<const float4*>(x + j0);
    float4 xa = xp[0];
    float4 xb = xp[1];
    float xs[PPT] = { xa.x, xa.y, xa.z, xa.w, xb.x, xb.y, xb.z, xb.w };

    float mu[2*PPT], sg[3*PPT];

#pragma unroll
    for (int q = 0; q < PPT; ++q) {
        float u  = xs[q] * 30.0f;
        float fi = fminf(fmaxf(floorf(u), 0.0f), 29.0f);
        int   i  = (int)fi;
        float d  = (u - fi) * 0.5f;          // [0, 0.5)

        // cw = cos^2(pi d) = (1 + cos(2 pi d))/2 ; v_cos_f32 arg in revolutions
        float cw  = 0.5f + 0.5f*__builtin_amdgcn_cosf(d);
        float sw  = 1.0f - cw;
        float cw2 = cw*cw, sw2 = sw*sw;

        float omd  = 1.0f - d;            // 1-d
        float om2d = 1.0f - 2.0f*d;       // 1-2d
        float g    = d * om2d;            // d(1-2d)
        float w0 = -cw * g;
        float w3 = -sw * g;
        float w1 = cw*(1.0f - 4.0f*d*d) + sw*omd*om2d;
        float w2 = cw*d*(1.0f + 2.0f*d) + 4.0f*sw*d*omd;

        float hp = 0.5f + d;              // d+0.5
        float q14 = 1.0f - 4.0f*d*d;      // (1-4d^2)
        float v0 = -cw2 * g * (0.5f - d);
        float v3 = -sw2 * g * d;
        float v1 = cw2*q14*q14 + sw2*omd*omd*om2d;
        float v2 = cw2*2.0f*d*hp*hp + 16.0f*sw2*d*d*omd*omd;

        uint2 rpx = qtab[0][i];
        uint2 rpy = qtab[1][i];
        uint2 rs0 = qtab[2][i];
        uint2 rs1 = qtab[3][i];
        uint2 rs2 = qtab[4][i];

        mu[2*q+0] = w0*bflo(rpx.x) + w1*bfhi(rpx.x) + w2*bflo(rpx.y) + w3*bfhi(rpx.y);
        mu[2*q+1] = w0*bflo(rpy.x) + w1*bfhi(rpy.x) + w2*bflo(rpy.y) + w3*bfhi(rpy.y);
        sg[3*q+0] = v0*bflo(rs0.x) + v1*bfhi(rs0.x) + v2*bflo(rs0.y) + v3*bfhi(rs0.y);
        sg[3*q+1] = v0*bflo(rs1.x) + v1*bfhi(rs1.x) + v2*bflo(rs1.y) + v3*bfhi(rs1.y);
        sg[3*q+2] = v0*bflo(rs2.x) + v1*bfhi(rs2.x) + v2*bflo(rs2.y) + v3*bfhi(rs2.y);
    }

    // mu region: [2*j0, 2*j0+16) -> 4 float4 stores
    float4* muOut = reinterpret_cast<float4*>(out + 2*j0);
#pragma unroll
    for (int k = 0; k < PPT/2; ++k)
        muOut[k] = make_float4(mu[4*k], mu[4*k+1], mu[4*k+2], mu[4*k+3]);
    // sg region: [2N + 3*j0, +24) -> 6 float4 stores
    float4* sgOut = reinterpret_cast<float4*>(out + (size_t)2*N + 3*j0);
#pragma unroll
    for (int k = 0; k < (3*PPT)/4; ++k)
        sgOut[k] = make_float4(sg[4*k], sg[4*k+1], sg[4*k+2], sg[4*k+3]);
}

extern "C" void kernel_launch(void* const* d_in, const int* in_sizes, int n_in,
                              void* d_out, int out_size, void* d_ws, size_t ws_size,
                              hipStream_t stream) {
    const float* x = (const float*)d_in[0];
    const float* P = (const float*)d_in[1];
    float* out = (float*)d_out;
    int N = in_sizes[0];

    const int threads = 256;
    const int per_block = threads * PPT;
    int blocks = (N + per_block - 1) / per_block;
    yuksel_fused<<<blocks, threads, 0, stream>>>(x, P, out, N);
}

// Round 12
// 28.837 us; speedup vs baseline: 1.1839x; 1.1839x over previous
//
#include <hip/hip_runtime.h>
#include <math.h>

#define NENT 33          // tap entries 0..32
#define NQ   30          // quad records e = taps (e..e+3), e = 0..29
#define PPT  4
#define NBLK 2048

__device__ __forceinline__ unsigned short f2bf(float f) {
    unsigned int b = __float_as_uint(f);
    unsigned int r = (b + 0x7FFFu + ((b >> 16) & 1u)) >> 16;   // RNE
    return (unsigned short)r;
}
__device__ __forceinline__ float bflo(unsigned int w) { return __uint_as_float(w << 16); }
__device__ __forceinline__ float bfhi(unsigned int w) { return __uint_as_float(w & 0xFFFF0000u); }

__global__ __launch_bounds__(256, 8) void yuksel_fused(
    const float* __restrict__ x, const float* __restrict__ P,
    float* __restrict__ out, int N)
{
    __shared__ float stage[5][NENT];
    __shared__ uint2 qtab[5][NQ];     // bf16x4: taps e..e+3, one ds_read_b64 each
    const int tid = threadIdx.x;

    // ---- phase A: 33 parallel entry tasks ----
    if (tid < NENT) {
        const int e = tid;
        float vals[5];
        if (e == 1) {
            float r0[5], r1[5], r2[5];
            for (int r = 0; r < 3; ++r) {
                float* dst = r==0 ? r0 : (r==1 ? r1 : r2);
                float a = P[r*5+2], b = P[r*5+3], c = P[r*5+4];
                dst[0] = P[r*5+0]; dst[1] = P[r*5+1];
                dst[2] = a*a + b*b; dst[3] = b*(a+c); dst[4] = b*b + c*c;
            }
            for (int k = 0; k < 2; ++k) vals[k] = (r0[k]+r2[k])*0.25f   + r1[k]*0.5f;
            for (int k = 2; k < 5; ++k) vals[k] = (r0[k]+r2[k])*0.0625f + r1[k]*0.25f;
        } else {
            float a = P[e*5+2], b = P[e*5+3], c = P[e*5+4];
            vals[0] = P[e*5+0]; vals[1] = P[e*5+1];
            vals[2] = a*a + b*b; vals[3] = b*(a+c); vals[4] = b*b + c*c;
        }
#pragma unroll
        for (int k = 0; k < 5; ++k) stage[k][e] = vals[k];
    }
    __syncthreads();

    // ---- phase B: 150 parallel bf16x4 pack tasks ----
    if (tid < 5*NQ) {
        const int k = tid / NQ, e = tid % NQ;
        unsigned int h0 = f2bf(stage[k][e+0]), h1 = f2bf(stage[k][e+1]);
        unsigned int h2 = f2bf(stage[k][e+2]), h3 = f2bf(stage[k][e+3]);
        qtab[k][e] = make_uint2(h0 | (h1 << 16), h2 | (h3 << 16));
    }
    __syncthreads();

    // ---- eval: 4 pts/thread, 2-deep read pipeline across grid-stride iters ----
    auto process = [&](float4 xv, long long j0) {
        float xs[PPT] = { xv.x, xv.y, xv.z, xv.w };
        float mu[2*PPT], sg[3*PPT];
#pragma unroll
        for (int q = 0; q < PPT; ++q) {
            float u  = xs[q] * 30.0f;
            float fi = fminf(fmaxf(floorf(u), 0.0f), 29.0f);
            int   i  = (int)fi;
            float d  = (u - fi) * 0.5f;          // [0, 0.5)

            // cw = cos^2(pi d) = (1 + cos(2 pi d))/2 ; v_cos_f32 arg in revolutions
            float cw  = 0.5f + 0.5f*__builtin_amdgcn_cosf(d);
            float sw  = 1.0f - cw;
            float cw2 = cw*cw, sw2 = sw*sw;

            float omd  = 1.0f - d;
            float om2d = 1.0f - 2.0f*d;
            float g    = d * om2d;
            float w0 = -cw * g;
            float w3 = -sw * g;
            float w1 = cw*(1.0f - 4.0f*d*d) + sw*omd*om2d;
            float w2 = cw*d*(1.0f + 2.0f*d) + 4.0f*sw*d*omd;

            float hp  = 0.5f + d;
            float q14 = 1.0f - 4.0f*d*d;
            float v0 = -cw2 * g * (0.5f - d);
            float v3 = -sw2 * g * d;
            float v1 = cw2*q14*q14 + sw2*omd*omd*om2d;
            float v2 = cw2*2.0f*d*hp*hp + 16.0f*sw2*d*d*omd*omd;

            uint2 rpx = qtab[0][i];
            uint2 rpy = qtab[1][i];
            uint2 rs0 = qtab[2][i];
            uint2 rs1 = qtab[3][i];
            uint2 rs2 = qtab[4][i];

            mu[2*q+0] = w0*bflo(rpx.x) + w1*bfhi(rpx.x) + w2*bflo(rpx.y) + w3*bfhi(rpx.y);
            mu[2*q+1] = w0*bflo(rpy.x) + w1*bfhi(rpy.x) + w2*bflo(rpy.y) + w3*bfhi(rpy.y);
            sg[3*q+0] = v0*bflo(rs0.x) + v1*bfhi(rs0.x) + v2*bflo(rs0.y) + v3*bfhi(rs0.y);
            sg[3*q+1] = v0*bflo(rs1.x) + v1*bfhi(rs1.x) + v2*bflo(rs1.y) + v3*bfhi(rs1.y);
            sg[3*q+2] = v0*bflo(rs2.x) + v1*bfhi(rs2.x) + v2*bflo(rs2.y) + v3*bfhi(rs2.y);
        }
        float4* muOut = reinterpret_cast<float4*>(out + 2*j0);
        muOut[0] = make_float4(mu[0], mu[1], mu[2], mu[3]);
        muOut[1] = make_float4(mu[4], mu[5], mu[6], mu[7]);
        float4* sgOut = reinterpret_cast<float4*>(out + (size_t)2*N + 3*j0);
        sgOut[0] = make_float4(sg[0], sg[1], sg[2],  sg[3]);
        sgOut[1] = make_float4(sg[4], sg[5], sg[6],  sg[7]);
        sgOut[2] = make_float4(sg[8], sg[9], sg[10], sg[11]);
    };

    const long long stride = (long long)gridDim.x * 256 * PPT;
    long long j0 = ((long long)blockIdx.x * 256 + tid) * PPT;
    if (j0 >= N) return;

    // iteration 1 + 2 loads issued back-to-back (2x read MLP)
    float4 xv0 = *reinterpret_cast<const float4*>(x + j0);
    long long j1 = j0 + stride;
    float4 xv1;
    bool has2 = (j1 < N);
    if (has2) xv1 = *reinterpret_cast<const float4*>(x + j1);

    process(xv0, j0);
    if (has2) process(xv1, j1);

    // generic tail (empty for N = 2048*256*4*2)
    for (long long j = j1 + stride; j < N; j += stride) {
        float4 xv = *reinterpret_cast<const float4*>(x + j);
        process(xv, j);
    }
}

extern "C" void kernel_launch(void* const* d_in, const int* in_sizes, int n_in,
                              void* d_out, int out_size, void* d_ws, size_t ws_size,
                              hipStream_t stream) {
    const float* x = (const float*)d_in[0];
    const float* P = (const float*)d_in[1];
    float* out = (float*)d_out;
    int N = in_sizes[0];

    const int threads = 256;
    const int per_block = threads * PPT;
    long long ntiles = (N + per_block - 1) / per_block;
    int blocks = (int)(ntiles < NBLK ? ntiles : NBLK);
    yuksel_fused<<<blocks, threads, 0, stream>>>(x, P, out, N);
}

// Round 13
// 25.117 us; speedup vs baseline: 1.3592x; 1.1481x over previous
//
#include <hip/hip_runtime.h>
#include <math.h>

#define NENT 33          // tap entries 0..32
#define NQ   30          // quad records e = taps (e..e+3), e = 0..29
#define NBLK 2048
#define WPB  4           // waves per block
#define CHUNK 256        // points per wave-chunk (64 lanes x 4 pts)

__device__ __forceinline__ unsigned short f2bf(float f) {
    unsigned int b = __float_as_uint(f);
    unsigned int r = (b + 0x7FFFu + ((b >> 16) & 1u)) >> 16;   // RNE
    return (unsigned short)r;
}
__device__ __forceinline__ float bflo(unsigned int w) { return __uint_as_float(w << 16); }
__device__ __forceinline__ float bfhi(unsigned int w) { return __uint_as_float(w & 0xFFFF0000u); }

__global__ __launch_bounds__(256) void yuksel_fused(
    const float* __restrict__ x, const float* __restrict__ P,
    float* __restrict__ out, int N)
{
    __shared__ float stage[5][NENT];
    __shared__ uint2 qtab[5][NQ];        // bf16x4 taps
    __shared__ float sgbuf[WPB][3*CHUNK]; // per-wave sg staging (12 KB)
    const int tid  = threadIdx.x;
    const int lane = tid & 63;
    const int wave = tid >> 6;

    // ---- phase A: 33 parallel entry tasks ----
    if (tid < NENT) {
        const int e = tid;
        float vals[5];
        if (e == 1) {
            float r0[5], r1[5], r2[5];
            for (int r = 0; r < 3; ++r) {
                float* dst = r==0 ? r0 : (r==1 ? r1 : r2);
                float a = P[r*5+2], b = P[r*5+3], c = P[r*5+4];
                dst[0] = P[r*5+0]; dst[1] = P[r*5+1];
                dst[2] = a*a + b*b; dst[3] = b*(a+c); dst[4] = b*b + c*c;
            }
            for (int k = 0; k < 2; ++k) vals[k] = (r0[k]+r2[k])*0.25f   + r1[k]*0.5f;
            for (int k = 2; k < 5; ++k) vals[k] = (r0[k]+r2[k])*0.0625f + r1[k]*0.25f;
        } else {
            float a = P[e*5+2], b = P[e*5+3], c = P[e*5+4];
            vals[0] = P[e*5+0]; vals[1] = P[e*5+1];
            vals[2] = a*a + b*b; vals[3] = b*(a+c); vals[4] = b*b + c*c;
        }
#pragma unroll
        for (int k = 0; k < 5; ++k) stage[k][e] = vals[k];
    }
    __syncthreads();

    // ---- phase B: 150 parallel bf16x4 pack tasks ----
    if (tid < 5*NQ) {
        const int k = tid / NQ, e = tid % NQ;
        unsigned int h0 = f2bf(stage[k][e+0]), h1 = f2bf(stage[k][e+1]);
        unsigned int h2 = f2bf(stage[k][e+2]), h3 = f2bf(stage[k][e+3]);
        qtab[k][e] = make_uint2(h0 | (h1 << 16), h2 | (h3 << 16));
    }
    __syncthreads();

    // ---- eval: lane-interleaved, all global accesses wave-contiguous ----
    const int gwave = blockIdx.x * WPB + wave;
    const long long chunk_stride = (long long)gridDim.x * WPB * CHUNK;

    for (long long base = (long long)gwave * CHUNK; base < N; base += chunk_stride) {
        const bool full = (base + CHUNK <= N);

        // 4 coalesced dword x-loads: lane L -> point base + 64q + L
        float xs[4];
#pragma unroll
        for (int q = 0; q < 4; ++q) {
            long long p = base + q*64 + lane;
            xs[q] = (full || p < N) ? x[p] : 0.0f;
        }

        float m0[4], m1[4], sv0[4], sv1[4], sv2[4];
#pragma unroll
        for (int q = 0; q < 4; ++q) {
            float u  = xs[q] * 30.0f;
            float fi = fminf(fmaxf(floorf(u), 0.0f), 29.0f);
            int   i  = (int)fi;
            float d  = (u - fi) * 0.5f;          // [0, 0.5)

            float cw  = 0.5f + 0.5f*__builtin_amdgcn_cosf(d);
            float sw  = 1.0f - cw;
            float cw2 = cw*cw, sw2 = sw*sw;

            float omd  = 1.0f - d;
            float om2d = 1.0f - 2.0f*d;
            float g    = d * om2d;
            float w0 = -cw * g;
            float w3 = -sw * g;
            float w1 = cw*(1.0f - 4.0f*d*d) + sw*omd*om2d;
            float w2 = cw*d*(1.0f + 2.0f*d) + 4.0f*sw*d*omd;

            float hp  = 0.5f + d;
            float q14 = 1.0f - 4.0f*d*d;
            float v0 = -cw2 * g * (0.5f - d);
            float v3 = -sw2 * g * d;
            float v1 = cw2*q14*q14 + sw2*omd*omd*om2d;
            float v2 = cw2*2.0f*d*hp*hp + 16.0f*sw2*d*d*omd*omd;

            uint2 rpx = qtab[0][i];
            uint2 rpy = qtab[1][i];
            uint2 rs0 = qtab[2][i];
            uint2 rs1 = qtab[3][i];
            uint2 rs2 = qtab[4][i];

            m0[q]  = w0*bflo(rpx.x) + w1*bfhi(rpx.x) + w2*bflo(rpx.y) + w3*bfhi(rpx.y);
            m1[q]  = w0*bflo(rpy.x) + w1*bfhi(rpy.x) + w2*bflo(rpy.y) + w3*bfhi(rpy.y);
            sv0[q] = v0*bflo(rs0.x) + v1*bfhi(rs0.x) + v2*bflo(rs0.y) + v3*bfhi(rs0.y);
            sv1[q] = v0*bflo(rs1.x) + v1*bfhi(rs1.x) + v2*bflo(rs1.y) + v3*bfhi(rs1.y);
            sv2[q] = v0*bflo(rs2.x) + v1*bfhi(rs2.x) + v2*bflo(rs2.y) + v3*bfhi(rs2.y);
        }

        if (full) {
            // mu: 4x store_dwordx2, lane-contiguous 512B per instr
#pragma unroll
            for (int q = 0; q < 4; ++q) {
                float2 v = make_float2(m0[q], m1[q]);
                *reinterpret_cast<float2*>(out + 2*(base + q*64) + 2*lane) = v;
            }
            // sg: stage in per-wave LDS, read back linear, 3x contiguous dwordx4
#pragma unroll
            for (int q = 0; q < 4; ++q) {
                float* sb = &sgbuf[wave][(q*64 + lane)*3];
                sb[0] = sv0[q]; sb[1] = sv1[q]; sb[2] = sv2[q];
            }
            __builtin_amdgcn_sched_barrier(0);   // keep reads after writes; DS in-order per wave
            float* sgOutBase = out + (size_t)2*N + 3*base;
#pragma unroll
            for (int k = 0; k < 3; ++k) {
                float4 v = *reinterpret_cast<const float4*>(&sgbuf[wave][k*256 + lane*4]);
                *reinterpret_cast<float4*>(sgOutBase + k*256 + lane*4) = v;
            }
        } else {
            // masked tail (unused for N % 256 == 0)
#pragma unroll
            for (int q = 0; q < 4; ++q) {
                long long p = base + q*64 + lane;
                if (p < N) {
                    out[2*p+0] = m0[q]; out[2*p+1] = m1[q];
                    float* so = out + (size_t)2*N + 3*p;
                    so[0] = sv0[q]; so[1] = sv1[q]; so[2] = sv2[q];
                }
            }
        }
    }
}

extern "C" void kernel_launch(void* const* d_in, const int* in_sizes, int n_in,
                              void* d_out, int out_size, void* d_ws, size_t ws_size,
                              hipStream_t stream) {
    const float* x = (const float*)d_in[0];
    const float* P = (const float*)d_in[1];
    float* out = (float*)d_out;
    int N = in_sizes[0];

    const int threads = 256;
    const int per_block = threads * 4;           // 1024 points per block-pass
    long long ntiles = ((long long)N + per_block - 1) / per_block;
    int blocks = (int)(ntiles < NBLK ? ntiles : NBLK);
    yuksel_fused<<<blocks, threads, 0, stream>>>(x, P, out, N);
}